// Round 1
// baseline (283.810 us; speedup 1.0000x reference)
//
#include <hip/hip_runtime.h>
#include <hip/hip_bf16.h>

// Problem: SelfAttention1d  B=16, C=512, L=1024
// Pipeline:
//  1) bn_stats: per-channel mean/var over (B,L) -> scale/shift
//  2) cast_w: fp32 weights -> bf16 (natural [m][k] row-major = A-operand layout)
//  3) norm_t: hn = x*scale+shift, written TRANSPOSED as hnT [B][L][C] (bf16)
//  4) gemm (MODE1): qT,kT = (W hn)^T -> [B][L][C]   (A=W [m][k], B=hnT [n][k])
//     gemm (MODE0): v = W hn -> [B][C][L]
//  5) gemm (MODE2): S = qT kT^T * C^-0.5 -> fp32 [B][L][L]
//  6) softmax_rows in-place: S row (fp32) -> attn row (bf16, aliased at row start)
//  7) gemm (MODE0): HT = attn v^T -> [B][L][C]  (A=attn [i][j], B=v [c][j])
//  8) gemm (MODE3): out = Wp HT^T + bp + x -> fp32 [B][C][L]
//
// GEMM core: 128x128 tile, BK=32, 256 thr (4 waves, each 64x64 as 4x4 of
// 16x16x32 MFMA), global_load_lds width=16 staging, LDS [row][k] k-contiguous.

#define BB 16
#define CC 512
#define LL 1024

typedef __bf16 bf16x8 __attribute__((ext_vector_type(8)));
typedef float  f32x4  __attribute__((ext_vector_type(4)));

__device__ inline unsigned short bf16_bits(float f) {
  __hip_bfloat16 h = __float2bfloat16(f);
  return __builtin_bit_cast(unsigned short, h);
}

// ---------------- BN stats: one block per channel ----------------
__global__ __launch_bounds__(256) void bn_stats(
    const float* __restrict__ x, const float* __restrict__ gamma,
    const float* __restrict__ beta, float* __restrict__ scl,
    float* __restrict__ sft) {
  int c = blockIdx.x;
  int t = threadIdx.x;
  float s = 0.f, s2 = 0.f;
  for (int b = 0; b < BB; ++b) {
    float4 v = ((const float4*)(x + ((size_t)(b * CC + c)) * LL))[t];
    s  += v.x + v.y + v.z + v.w;
    s2 += v.x * v.x + v.y * v.y + v.z * v.z + v.w * v.w;
  }
  for (int m = 32; m; m >>= 1) { s += __shfl_xor(s, m, 64); s2 += __shfl_xor(s2, m, 64); }
  __shared__ float rs[4], rs2[4];
  int wave = t >> 6, lane = t & 63;
  if (lane == 0) { rs[wave] = s; rs2[wave] = s2; }
  __syncthreads();
  if (t == 0) {
    float S  = rs[0] + rs[1] + rs[2] + rs[3];
    float S2 = rs2[0] + rs2[1] + rs2[2] + rs2[3];
    float mean = S * (1.f / 16384.f);
    float var  = S2 * (1.f / 16384.f) - mean * mean;
    float sc = gamma[c] * rsqrtf(var + 1e-5f);
    scl[c] = sc;
    sft[c] = beta[c] - mean * sc;
  }
}

// ---------------- weight cast fp32 -> bf16 ----------------
__global__ __launch_bounds__(256) void cast_w(const float* __restrict__ src,
                                              __hip_bfloat16* __restrict__ dst) {
  int i = blockIdx.x * 256 + threadIdx.x;
  float4 v = ((const float4*)src)[i];
  ushort4 o;
  o.x = bf16_bits(v.x); o.y = bf16_bits(v.y);
  o.z = bf16_bits(v.z); o.w = bf16_bits(v.w);
  ((ushort4*)dst)[i] = o;
}

// ---------------- normalize + transpose: x [B][C][L] -> hnT [B][L][C] bf16 ----
__global__ __launch_bounds__(256) void norm_t(
    const float* __restrict__ x, const float* __restrict__ scl,
    const float* __restrict__ sft, __hip_bfloat16* __restrict__ hnT) {
  __shared__ float tile[32][33];
  int l0 = blockIdx.x * 32, c0 = blockIdx.y * 32, b = blockIdx.z;
  int t = threadIdx.x;
#pragma unroll
  for (int i = 0; i < 4; ++i) {
    int idx = t + i * 256;
    int cc = idx >> 5, ll = idx & 31;
    tile[cc][ll] = x[((size_t)(b * CC + c0 + cc)) * LL + l0 + ll];
  }
  __syncthreads();
#pragma unroll
  for (int i = 0; i < 4; ++i) {
    int idx = t + i * 256;
    int ll = idx >> 5, cc = idx & 31;
    float v = tile[cc][ll] * scl[c0 + cc] + sft[c0 + cc];
    hnT[((size_t)(b * LL + l0 + ll)) * CC + c0 + cc] = __float2bfloat16(v);
  }
}

// ---------------- softmax, in-place fp32 row -> bf16 row ----------------
__global__ __launch_bounds__(256) void softmax_rows(float* __restrict__ S) {
  size_t row = blockIdx.x;
  float* p = S + row * 1024;
  int t = threadIdx.x, wave = t >> 6, lane = t & 63;
  float4 v = ((const float4*)p)[t];
  float mx = fmaxf(fmaxf(v.x, v.y), fmaxf(v.z, v.w));
  for (int m = 32; m; m >>= 1) mx = fmaxf(mx, __shfl_xor(mx, m, 64));
  __shared__ float red[4];
  if (lane == 0) red[wave] = mx;
  __syncthreads();
  mx = fmaxf(fmaxf(red[0], red[1]), fmaxf(red[2], red[3]));
  __syncthreads();
  float e0 = __expf(v.x - mx), e1 = __expf(v.y - mx);
  float e2 = __expf(v.z - mx), e3 = __expf(v.w - mx);
  float s = e0 + e1 + e2 + e3;
  for (int m = 32; m; m >>= 1) s += __shfl_xor(s, m, 64);
  if (lane == 0) red[wave] = s;
  __syncthreads();
  s = red[0] + red[1] + red[2] + red[3];
  float inv = 1.f / s;
  ushort4 o;
  o.x = bf16_bits(e0 * inv); o.y = bf16_bits(e1 * inv);
  o.z = bf16_bits(e2 * inv); o.w = bf16_bits(e3 * inv);
  ((ushort4*)p)[t] = o;  // first half of the row; reads all done (barriers above)
}

// ---------------- GEMM: D[m][n] = sum_k A[m][k]*B[n][k], batched ----------------
// MODE 0: bf16 natural D[m*ldd+n] (+bias)
// MODE 1: bf16 transposed D[n*ldd+m] (+bias), packed 8B stores
// MODE 2: fp32 natural, *scale
// MODE 3: fp32 natural, +bias +resid
template <int MODE, bool BIAS>
__global__ __launch_bounds__(256) void gemm_tn(
    const __hip_bfloat16* __restrict__ A, int lda, size_t strideA,
    const __hip_bfloat16* __restrict__ B, int ldb, size_t strideB,
    void* __restrict__ Dp, int ldd, size_t strideD,
    const float* __restrict__ bias, float scale,
    const float* __restrict__ resid, size_t strideR, int K) {
  __shared__ __align__(16) __hip_bfloat16 sA[128 * 32];
  __shared__ __align__(16) __hip_bfloat16 sB[128 * 32];
  const int bat = blockIdx.z;
  const int m0 = blockIdx.y * 128, n0 = blockIdx.x * 128;
  const int tid = threadIdx.x;
  const int wave = tid >> 6, lane = tid & 63;
  const int wm = (wave >> 1) * 64, wn = (wave & 1) * 64;
  A += (size_t)bat * strideA;
  B += (size_t)bat * strideB;

  f32x4 acc[4][4] = {};

  const int row0 = tid >> 2;       // 0..63
  const int ke0  = (tid & 3) * 8;  // element offset within 32-wide k slab

  for (int k0 = 0; k0 < K; k0 += 32) {
    __syncthreads();
#pragma unroll
    for (int it = 0; it < 2; ++it) {
      int row = it * 64 + row0;
      const __hip_bfloat16* ga = A + (size_t)(m0 + row) * lda + (k0 + ke0);
      const __hip_bfloat16* gb = B + (size_t)(n0 + row) * ldb + (k0 + ke0);
      __builtin_amdgcn_global_load_lds(
          (__attribute__((address_space(1))) void*)(void*)ga,
          (__attribute__((address_space(3))) void*)(sA + (it * 256 + wave * 64) * 8),
          16, 0, 0);
      __builtin_amdgcn_global_load_lds(
          (__attribute__((address_space(1))) void*)(void*)gb,
          (__attribute__((address_space(3))) void*)(sB + (it * 256 + wave * 64) * 8),
          16, 0, 0);
    }
    __syncthreads();
    bf16x8 af[4], bfr[4];
    const int kq = (lane >> 4) * 8;
    const int fr = lane & 15;
#pragma unroll
    for (int i = 0; i < 4; ++i) {
      af[i]  = *(const bf16x8*)(sA + (wm + i * 16 + fr) * 32 + kq);
      bfr[i] = *(const bf16x8*)(sB + (wn + i * 16 + fr) * 32 + kq);
    }
#pragma unroll
    for (int i = 0; i < 4; ++i)
#pragma unroll
      for (int j = 0; j < 4; ++j)
        acc[i][j] = __builtin_amdgcn_mfma_f32_16x16x32_bf16(af[i], bfr[j], acc[i][j], 0, 0, 0);
  }

  const int crow = (lane >> 4) * 4;  // D row group
  const int ccol = lane & 15;        // D col
  if constexpr (MODE == 0 || MODE == 1) {
    __hip_bfloat16* D = (__hip_bfloat16*)Dp + (size_t)bat * strideD;
#pragma unroll
    for (int i = 0; i < 4; ++i) {
      int mg = m0 + wm + i * 16 + crow;
      float bv[4];
#pragma unroll
      for (int r = 0; r < 4; ++r) bv[r] = BIAS ? bias[mg + r] : 0.f;
#pragma unroll
      for (int j = 0; j < 4; ++j) {
        int ng = n0 + wn + j * 16 + ccol;
        if constexpr (MODE == 0) {
#pragma unroll
          for (int r = 0; r < 4; ++r)
            D[(size_t)(mg + r) * ldd + ng] = __float2bfloat16(acc[i][j][r] * scale + bv[r]);
        } else {
          ushort4 o;
          o.x = bf16_bits(acc[i][j][0] * scale + bv[0]);
          o.y = bf16_bits(acc[i][j][1] * scale + bv[1]);
          o.z = bf16_bits(acc[i][j][2] * scale + bv[2]);
          o.w = bf16_bits(acc[i][j][3] * scale + bv[3]);
          *(ushort4*)(D + (size_t)ng * ldd + mg) = o;
        }
      }
    }
  } else {
    float* D = (float*)Dp + (size_t)bat * strideD;
#pragma unroll
    for (int i = 0; i < 4; ++i) {
      int mg = m0 + wm + i * 16 + crow;
      float bv[4];
#pragma unroll
      for (int r = 0; r < 4; ++r) bv[r] = BIAS ? bias[mg + r] : 0.f;
#pragma unroll
      for (int j = 0; j < 4; ++j) {
        int ng = n0 + wn + j * 16 + ccol;
#pragma unroll
        for (int r = 0; r < 4; ++r) {
          float val = acc[i][j][r] * scale + bv[r];
          if constexpr (MODE == 3)
            val += resid[(size_t)bat * strideR + (size_t)(mg + r) * ldd + ng];
          D[(size_t)(mg + r) * ldd + ng] = val;
        }
      }
    }
  }
}

extern "C" void kernel_launch(void* const* d_in, const int* in_sizes, int n_in,
                              void* d_out, int out_size, void* d_ws, size_t ws_size,
                              hipStream_t stream) {
  const float* x     = (const float*)d_in[0];
  const float* gamma = (const float*)d_in[1];
  const float* beta  = (const float*)d_in[2];
  const float* Wq    = (const float*)d_in[3];
  const float* bq    = (const float*)d_in[4];
  const float* Wk    = (const float*)d_in[5];
  const float* bk    = (const float*)d_in[6];
  const float* Wv    = (const float*)d_in[7];
  const float* bv    = (const float*)d_in[8];
  const float* Wp    = (const float*)d_in[9];
  const float* bp    = (const float*)d_in[10];
  float* out = (float*)d_out;

  char* ws = (char*)d_ws;
  float* scl = (float*)ws;        // 512 f32
  float* sft = scl + 512;         // 512 f32
  __hip_bfloat16* Wqb = (__hip_bfloat16*)(ws + 4096);
  __hip_bfloat16* Wkb = Wqb + 262144;
  __hip_bfloat16* Wvb = Wkb + 262144;
  __hip_bfloat16* Wpb = Wvb + 262144;
  __hip_bfloat16* hnT = Wpb + 262144;     // [B][L][C] 8388608 elems
  __hip_bfloat16* qT  = hnT + 8388608;    // [B][L][C]
  __hip_bfloat16* kT  = qT + 8388608;     // [B][L][C]
  __hip_bfloat16* vN  = kT + 8388608;     // [B][C][L]
  float* S = (float*)(vN + 8388608);      // [B][L][L] fp32, attn aliases rows
  __hip_bfloat16* HT = hnT;               // reuse: hnT dead after QKV

  bn_stats<<<512, 256, 0, stream>>>(x, gamma, beta, scl, sft);
  cast_w<<<256, 256, 0, stream>>>(Wq, Wqb);
  cast_w<<<256, 256, 0, stream>>>(Wk, Wkb);
  cast_w<<<256, 256, 0, stream>>>(Wv, Wvb);
  cast_w<<<256, 256, 0, stream>>>(Wp, Wpb);
  norm_t<<<dim3(32, 16, 16), 256, 0, stream>>>(x, scl, sft, hnT);

  const size_t sLC = (size_t)LL * CC;   // 524288
  const size_t sCL = (size_t)CC * LL;
  const size_t sLL = (size_t)LL * LL;   // S per batch (fp32 elems)

  // qT = (Wq hn)^T  [L][C]
  gemm_tn<1, true><<<dim3(8, 4, 16), 256, 0, stream>>>(
      Wqb, 512, 0, hnT, 512, sLC, qT, 512, sLC, bq, 1.f, nullptr, 0, 512);
  // kT
  gemm_tn<1, true><<<dim3(8, 4, 16), 256, 0, stream>>>(
      Wkb, 512, 0, hnT, 512, sLC, kT, 512, sLC, bk, 1.f, nullptr, 0, 512);
  // v natural [C][L]
  gemm_tn<0, true><<<dim3(8, 4, 16), 256, 0, stream>>>(
      Wvb, 512, 0, hnT, 512, sLC, vN, 1024, sCL, bv, 1.f, nullptr, 0, 512);
  // S = qT kT^T * C^-0.5, fp32 [L][L]
  gemm_tn<2, false><<<dim3(8, 8, 16), 256, 0, stream>>>(
      qT, 512, sLC, kT, 512, sLC, S, 1024, sLL, nullptr,
      0.04419417382415922f, nullptr, 0, 512);
  softmax_rows<<<16384, 256, 0, stream>>>(S);
  // HT = attn v^T -> [L][C] bf16 (attn rows aliased over S, lda in bf16 = 2048)
  gemm_tn<0, false><<<dim3(4, 8, 16), 256, 0, stream>>>(
      (const __hip_bfloat16*)S, 2048, (size_t)1024 * 2048, vN, 1024, sCL,
      HT, 512, sLC, nullptr, 1.f, nullptr, 0, 1024);
  // out = Wp HT^T + bp + x, fp32 [C][L]
  gemm_tn<3, true><<<dim3(8, 4, 16), 256, 0, stream>>>(
      Wpb, 512, 0, HT, 512, sLC, out, 1024, sCL, bp, 1.f, x, sCL, 512);
}

// Round 2
// 263.048 us; speedup vs baseline: 1.0789x; 1.0789x over previous
//
#include <hip/hip_runtime.h>
#include <hip/hip_bf16.h>

// SelfAttention1d  B=16, C=512, L=1024
// R2: bf16 score tensor (halves S write + softmax traffic), fused QKV GEMM,
//     wave-per-row barrier-free softmax, vectorized norm_t stores.

#define BB 16
#define CC 512
#define LL 1024

typedef __bf16 bf16x8 __attribute__((ext_vector_type(8)));
typedef float  f32x4  __attribute__((ext_vector_type(4)));

__device__ inline unsigned short bf16_bits(float f) {
  __hip_bfloat16 h = __float2bfloat16(f);
  return __builtin_bit_cast(unsigned short, h);
}
__device__ inline float bits_lo(unsigned int u) {
  return __builtin_bit_cast(float, u << 16);
}
__device__ inline float bits_hi(unsigned int u) {
  return __builtin_bit_cast(float, u & 0xffff0000u);
}

// ---------------- BN stats: one block per channel ----------------
__global__ __launch_bounds__(256) void bn_stats(
    const float* __restrict__ x, const float* __restrict__ gamma,
    const float* __restrict__ beta, float* __restrict__ scl,
    float* __restrict__ sft) {
  int c = blockIdx.x;
  int t = threadIdx.x;
  float s = 0.f, s2 = 0.f;
  for (int b = 0; b < BB; ++b) {
    float4 v = ((const float4*)(x + ((size_t)(b * CC + c)) * LL))[t];
    s  += v.x + v.y + v.z + v.w;
    s2 += v.x * v.x + v.y * v.y + v.z * v.z + v.w * v.w;
  }
  for (int m = 32; m; m >>= 1) { s += __shfl_xor(s, m, 64); s2 += __shfl_xor(s2, m, 64); }
  __shared__ float rs[4], rs2[4];
  int wave = t >> 6, lane = t & 63;
  if (lane == 0) { rs[wave] = s; rs2[wave] = s2; }
  __syncthreads();
  if (t == 0) {
    float S  = rs[0] + rs[1] + rs[2] + rs[3];
    float S2 = rs2[0] + rs2[1] + rs2[2] + rs2[3];
    float mean = S * (1.f / 16384.f);
    float var  = S2 * (1.f / 16384.f) - mean * mean;
    float sc = gamma[c] * rsqrtf(var + 1e-5f);
    scl[c] = sc;
    sft[c] = beta[c] - mean * sc;
  }
}

// ---------------- weight casts: Wq|Wk|Wv -> concat, Wp separate ----------------
__global__ __launch_bounds__(256) void cast4(
    const float* __restrict__ Wq, const float* __restrict__ Wk,
    const float* __restrict__ Wv, const float* __restrict__ Wp,
    __hip_bfloat16* __restrict__ Wqkv, __hip_bfloat16* __restrict__ Wpb) {
  int m = blockIdx.y;
  const float* src = m == 0 ? Wq : m == 1 ? Wk : m == 2 ? Wv : Wp;
  __hip_bfloat16* dst = m < 3 ? Wqkv + (size_t)m * 262144 : Wpb;
  int i = blockIdx.x * 256 + threadIdx.x;
  float4 v = ((const float4*)src)[i];
  ushort4 o;
  o.x = bf16_bits(v.x); o.y = bf16_bits(v.y);
  o.z = bf16_bits(v.z); o.w = bf16_bits(v.w);
  ((ushort4*)dst)[i] = o;
}

// ---------------- normalize + transpose: x [B][C][L] -> hnT [B][L][C] bf16 ----
__global__ __launch_bounds__(256) void norm_t(
    const float* __restrict__ x, const float* __restrict__ scl,
    const float* __restrict__ sft, __hip_bfloat16* __restrict__ hnT) {
  __shared__ float tile[32][33];
  int l0 = blockIdx.x * 32, c0 = blockIdx.y * 32, b = blockIdx.z;
  int t = threadIdx.x;
#pragma unroll
  for (int i = 0; i < 4; ++i) {
    int idx = t + i * 256;
    int cc = idx >> 5, ll = idx & 31;
    tile[cc][ll] = x[((size_t)(b * CC + c0 + cc)) * LL + l0 + ll];
  }
  __syncthreads();
#pragma unroll
  for (int i = 0; i < 2; ++i) {
    int idx = t + i * 256;
    int ll = idx >> 4, cc = (idx & 15) * 2;
    float v0 = tile[cc][ll] * scl[c0 + cc] + sft[c0 + cc];
    float v1 = tile[cc + 1][ll] * scl[c0 + cc + 1] + sft[c0 + cc + 1];
    ushort2 o; o.x = bf16_bits(v0); o.y = bf16_bits(v1);
    *(ushort2*)(hnT + ((size_t)(b * LL + l0 + ll)) * CC + c0 + cc) = o;
  }
}

// ---------------- softmax: one row per wave, bf16 in place ----------------
__global__ __launch_bounds__(256) void softmax_bf16(__hip_bfloat16* __restrict__ S) {
  int wave = threadIdx.x >> 6, lane = threadIdx.x & 63;
  size_t row = (size_t)blockIdx.x * 4 + wave;
  uint4* p = (uint4*)(S + row * 1024);  // 8 bf16 per uint4
  uint4 r0 = p[lane * 2], r1 = p[lane * 2 + 1];
  float f[16];
  unsigned int w[8] = {r0.x, r0.y, r0.z, r0.w, r1.x, r1.y, r1.z, r1.w};
#pragma unroll
  for (int i = 0; i < 8; ++i) { f[2 * i] = bits_lo(w[i]); f[2 * i + 1] = bits_hi(w[i]); }
  float mx = f[0];
#pragma unroll
  for (int i = 1; i < 16; ++i) mx = fmaxf(mx, f[i]);
  for (int m = 32; m; m >>= 1) mx = fmaxf(mx, __shfl_xor(mx, m, 64));
  float s = 0.f;
#pragma unroll
  for (int i = 0; i < 16; ++i) { f[i] = __expf(f[i] - mx); s += f[i]; }
  for (int m = 32; m; m >>= 1) s += __shfl_xor(s, m, 64);
  float inv = 1.f / s;
  unsigned int ow[8];
#pragma unroll
  for (int i = 0; i < 8; ++i) {
    unsigned int lo = bf16_bits(f[2 * i] * inv);
    unsigned int hi = bf16_bits(f[2 * i + 1] * inv);
    ow[i] = lo | (hi << 16);
  }
  uint4 o0 = {ow[0], ow[1], ow[2], ow[3]}, o1 = {ow[4], ow[5], ow[6], ow[7]};
  p[lane * 2] = o0; p[lane * 2 + 1] = o1;
}

// ---------------- GEMM core: acc[4][4] += A[128xK] * B[128xK]^T ----------------
// A,B pre-offset to tile origin; both [row][k] k-contiguous, 16B-aligned rows.
__device__ __forceinline__ void gemm_core(
    const __hip_bfloat16* __restrict__ A, int lda,
    const __hip_bfloat16* __restrict__ B, int ldb, int K,
    __hip_bfloat16* sA, __hip_bfloat16* sB, f32x4 (&acc)[4][4]) {
  const int tid = threadIdx.x;
  const int wave = tid >> 6, lane = tid & 63;
  const int wm = (wave >> 1) * 64, wn = (wave & 1) * 64;
  const int row0 = tid >> 2;
  const int ke0 = (tid & 3) * 8;
  const int kq = (lane >> 4) * 8;
  const int fr = lane & 15;
  for (int k0 = 0; k0 < K; k0 += 32) {
    __syncthreads();
#pragma unroll
    for (int it = 0; it < 2; ++it) {
      const __hip_bfloat16* ga = A + (size_t)(it * 64 + row0) * lda + (k0 + ke0);
      const __hip_bfloat16* gb = B + (size_t)(it * 64 + row0) * ldb + (k0 + ke0);
      __builtin_amdgcn_global_load_lds(
          (__attribute__((address_space(1))) void*)(void*)ga,
          (__attribute__((address_space(3))) void*)(sA + (it * 256 + wave * 64) * 8),
          16, 0, 0);
      __builtin_amdgcn_global_load_lds(
          (__attribute__((address_space(1))) void*)(void*)gb,
          (__attribute__((address_space(3))) void*)(sB + (it * 256 + wave * 64) * 8),
          16, 0, 0);
    }
    __syncthreads();
    bf16x8 af[4], bfr[4];
#pragma unroll
    for (int i = 0; i < 4; ++i) {
      af[i]  = *(const bf16x8*)(sA + (wm + i * 16 + fr) * 32 + kq);
      bfr[i] = *(const bf16x8*)(sB + (wn + i * 16 + fr) * 32 + kq);
    }
#pragma unroll
    for (int i = 0; i < 4; ++i)
#pragma unroll
      for (int j = 0; j < 4; ++j)
        acc[i][j] = __builtin_amdgcn_mfma_f32_16x16x32_bf16(af[i], bfr[j], acc[i][j], 0, 0, 0);
  }
}

// ---------------- fused QKV: [1536x512] x hnT -> qT,kT (transposed), v ---------
__global__ __launch_bounds__(256) void gemm_qkv(
    const __hip_bfloat16* __restrict__ Wb, const __hip_bfloat16* __restrict__ hnT,
    __hip_bfloat16* __restrict__ qT, __hip_bfloat16* __restrict__ kT,
    __hip_bfloat16* __restrict__ vN,
    const float* __restrict__ bq, const float* __restrict__ bk,
    const float* __restrict__ bv) {
  __shared__ __align__(16) __hip_bfloat16 sA[128 * 32];
  __shared__ __align__(16) __hip_bfloat16 sB[128 * 32];
  const int bat = blockIdx.z;
  const int m0 = blockIdx.y * 128, n0 = blockIdx.x * 128;
  f32x4 acc[4][4] = {};
  gemm_core(Wb + (size_t)m0 * 512, 512,
            hnT + (size_t)bat * LL * CC + (size_t)n0 * 512, 512, 512, sA, sB, acc);
  const int lane = threadIdx.x & 63, wave = threadIdx.x >> 6;
  const int wm = (wave >> 1) * 64, wn = (wave & 1) * 64;
  const int crow = (lane >> 4) * 4, ccol = lane & 15;
  const int id = m0 >> 9;
  const int mloc0 = m0 & 511;
  const float* bias = id == 0 ? bq : id == 1 ? bk : bv;
  if (id < 2) {
    __hip_bfloat16* D = (id == 0 ? qT : kT) + (size_t)bat * LL * CC;
#pragma unroll
    for (int i = 0; i < 4; ++i) {
      int mg = mloc0 + wm + i * 16 + crow;
      float bv4[4];
#pragma unroll
      for (int r = 0; r < 4; ++r) bv4[r] = bias[mg + r];
#pragma unroll
      for (int j = 0; j < 4; ++j) {
        int ng = n0 + wn + j * 16 + ccol;
        ushort4 o;
        o.x = bf16_bits(acc[i][j][0] + bv4[0]);
        o.y = bf16_bits(acc[i][j][1] + bv4[1]);
        o.z = bf16_bits(acc[i][j][2] + bv4[2]);
        o.w = bf16_bits(acc[i][j][3] + bv4[3]);
        *(ushort4*)(D + (size_t)ng * 512 + mg) = o;
      }
    }
  } else {
    __hip_bfloat16* D = vN + (size_t)bat * CC * LL;
#pragma unroll
    for (int i = 0; i < 4; ++i) {
      int mg = mloc0 + wm + i * 16 + crow;
      float bv4[4];
#pragma unroll
      for (int r = 0; r < 4; ++r) bv4[r] = bias[mg + r];
#pragma unroll
      for (int j = 0; j < 4; ++j) {
        int ng = n0 + wn + j * 16 + ccol;
#pragma unroll
        for (int r = 0; r < 4; ++r)
          D[(size_t)(mg + r) * 1024 + ng] = __float2bfloat16(acc[i][j][r] + bv4[r]);
      }
    }
  }
}

// ---------------- generic GEMM: MODE 0 bf16 natural, MODE 3 fp32 +bias+resid --
template <int MODE, bool BIAS>
__global__ __launch_bounds__(256) void gemm_tn(
    const __hip_bfloat16* __restrict__ A, int lda, size_t strideA,
    const __hip_bfloat16* __restrict__ B, int ldb, size_t strideB,
    void* __restrict__ Dp, int ldd, size_t strideD,
    const float* __restrict__ bias, float scale,
    const float* __restrict__ resid, size_t strideR, int K) {
  __shared__ __align__(16) __hip_bfloat16 sA[128 * 32];
  __shared__ __align__(16) __hip_bfloat16 sB[128 * 32];
  const int bat = blockIdx.z;
  const int m0 = blockIdx.y * 128, n0 = blockIdx.x * 128;
  f32x4 acc[4][4] = {};
  gemm_core(A + (size_t)bat * strideA + (size_t)m0 * lda, lda,
            B + (size_t)bat * strideB + (size_t)n0 * ldb, ldb, K, sA, sB, acc);
  const int lane = threadIdx.x & 63, wave = threadIdx.x >> 6;
  const int wm = (wave >> 1) * 64, wn = (wave & 1) * 64;
  const int crow = (lane >> 4) * 4, ccol = lane & 15;
  if constexpr (MODE == 0) {
    __hip_bfloat16* D = (__hip_bfloat16*)Dp + (size_t)bat * strideD;
#pragma unroll
    for (int i = 0; i < 4; ++i) {
      int mg = m0 + wm + i * 16 + crow;
      float bv4[4];
#pragma unroll
      for (int r = 0; r < 4; ++r) bv4[r] = BIAS ? bias[mg + r] : 0.f;
#pragma unroll
      for (int j = 0; j < 4; ++j) {
        int ng = n0 + wn + j * 16 + ccol;
#pragma unroll
        for (int r = 0; r < 4; ++r)
          D[(size_t)(mg + r) * ldd + ng] =
              __float2bfloat16(acc[i][j][r] * scale + bv4[r]);
      }
    }
  } else {
    float* D = (float*)Dp + (size_t)bat * strideD;
#pragma unroll
    for (int i = 0; i < 4; ++i) {
      int mg = m0 + wm + i * 16 + crow;
      float bv4[4];
#pragma unroll
      for (int r = 0; r < 4; ++r) bv4[r] = BIAS ? bias[mg + r] : 0.f;
#pragma unroll
      for (int j = 0; j < 4; ++j) {
        int ng = n0 + wn + j * 16 + ccol;
#pragma unroll
        for (int r = 0; r < 4; ++r) {
          float val = acc[i][j][r] * scale + bv4[r];
          val += resid[(size_t)bat * strideR + (size_t)(mg + r) * ldd + ng];
          D[(size_t)(mg + r) * ldd + ng] = val;
        }
      }
    }
  }
}

extern "C" void kernel_launch(void* const* d_in, const int* in_sizes, int n_in,
                              void* d_out, int out_size, void* d_ws, size_t ws_size,
                              hipStream_t stream) {
  const float* x     = (const float*)d_in[0];
  const float* gamma = (const float*)d_in[1];
  const float* beta  = (const float*)d_in[2];
  const float* Wq    = (const float*)d_in[3];
  const float* bq    = (const float*)d_in[4];
  const float* Wk    = (const float*)d_in[5];
  const float* bk    = (const float*)d_in[6];
  const float* Wv    = (const float*)d_in[7];
  const float* bv    = (const float*)d_in[8];
  const float* Wp    = (const float*)d_in[9];
  const float* bp    = (const float*)d_in[10];
  float* out = (float*)d_out;

  char* ws = (char*)d_ws;
  float* scl = (float*)ws;
  float* sft = scl + 512;
  __hip_bfloat16* Wqkvb = (__hip_bfloat16*)(ws + 4096);   // 1536x512
  __hip_bfloat16* Wpb = Wqkvb + 786432;                   // 512x512
  __hip_bfloat16* hnT = Wpb + 262144;                     // [B][L][C]
  __hip_bfloat16* qT  = hnT + 8388608;                    // [B][L][C]
  __hip_bfloat16* kT  = qT + 8388608;                     // [B][L][C]
  __hip_bfloat16* vN  = kT + 8388608;                     // [B][C][L]
  __hip_bfloat16* Sb  = vN + 8388608;                     // [B][L][L] bf16
  __hip_bfloat16* HT  = hnT;                              // reuse after QKV

  bn_stats<<<512, 256, 0, stream>>>(x, gamma, beta, scl, sft);
  cast4<<<dim3(256, 4), 256, 0, stream>>>(Wq, Wk, Wv, Wp, Wqkvb, Wpb);
  norm_t<<<dim3(32, 16, 16), 256, 0, stream>>>(x, scl, sft, hnT);

  const size_t sLC = (size_t)LL * CC;
  const size_t sCL = (size_t)CC * LL;
  const size_t sLLb = (size_t)LL * LL;

  // fused QKV
  gemm_qkv<<<dim3(8, 12, 16), 256, 0, stream>>>(Wqkvb, hnT, qT, kT, vN, bq, bk, bv);
  // S = qT kT^T * C^-0.5 -> bf16 [L][L]
  gemm_tn<0, false><<<dim3(8, 8, 16), 256, 0, stream>>>(
      qT, 512, sLC, kT, 512, sLC, Sb, 1024, sLLb, nullptr,
      0.04419417382415922f, nullptr, 0, 512);
  softmax_bf16<<<4096, 256, 0, stream>>>(Sb);
  // HT = attn v^T -> [L][C] bf16
  gemm_tn<0, false><<<dim3(4, 8, 16), 256, 0, stream>>>(
      Sb, 1024, sLLb, vN, 1024, sCL, HT, 512, sLC, nullptr, 1.f, nullptr, 0, 1024);
  // out = Wp HT^T + bp + x -> fp32 [C][L]
  gemm_tn<3, true><<<dim3(8, 4, 16), 256, 0, stream>>>(
      Wpb, 512, 0, HT, 512, sLC, out, 1024, sCL, bp, 1.f, x, sCL, 512);
}

// Round 3
// 244.183 us; speedup vs baseline: 1.1623x; 1.0773x over previous
//
#include <hip/hip_runtime.h>
#include <hip/hip_bf16.h>

// SelfAttention1d  B=16, C=512, L=1024
// R3: occupancy fix — __launch_bounds__(256,3) caps unified VGPR+AGPR at 170
//     (was 112+64=176 -> only 2 waves/SIMD); XOR bank swizzle on LDS k-chunks
//     kills the 8-way fragment-read conflict (3.1M cycles in R2).

#define BB 16
#define CC 512
#define LL 1024

typedef __bf16 bf16x8 __attribute__((ext_vector_type(8)));
typedef float  f32x4  __attribute__((ext_vector_type(4)));

__device__ inline unsigned short bf16_bits(float f) {
  __hip_bfloat16 h = __float2bfloat16(f);
  return __builtin_bit_cast(unsigned short, h);
}
__device__ inline float bits_lo(unsigned int u) {
  return __builtin_bit_cast(float, u << 16);
}
__device__ inline float bits_hi(unsigned int u) {
  return __builtin_bit_cast(float, u & 0xffff0000u);
}

// ---------------- BN stats: one block per channel ----------------
__global__ __launch_bounds__(256) void bn_stats(
    const float* __restrict__ x, const float* __restrict__ gamma,
    const float* __restrict__ beta, float* __restrict__ scl,
    float* __restrict__ sft) {
  int c = blockIdx.x;
  int t = threadIdx.x;
  float s = 0.f, s2 = 0.f;
  for (int b = 0; b < BB; ++b) {
    float4 v = ((const float4*)(x + ((size_t)(b * CC + c)) * LL))[t];
    s  += v.x + v.y + v.z + v.w;
    s2 += v.x * v.x + v.y * v.y + v.z * v.z + v.w * v.w;
  }
  for (int m = 32; m; m >>= 1) { s += __shfl_xor(s, m, 64); s2 += __shfl_xor(s2, m, 64); }
  __shared__ float rs[4], rs2[4];
  int wave = t >> 6, lane = t & 63;
  if (lane == 0) { rs[wave] = s; rs2[wave] = s2; }
  __syncthreads();
  if (t == 0) {
    float S  = rs[0] + rs[1] + rs[2] + rs[3];
    float S2 = rs2[0] + rs2[1] + rs2[2] + rs2[3];
    float mean = S * (1.f / 16384.f);
    float var  = S2 * (1.f / 16384.f) - mean * mean;
    float sc = gamma[c] * rsqrtf(var + 1e-5f);
    scl[c] = sc;
    sft[c] = beta[c] - mean * sc;
  }
}

// ---------------- weight casts: Wq|Wk|Wv -> concat, Wp separate ----------------
__global__ __launch_bounds__(256) void cast4(
    const float* __restrict__ Wq, const float* __restrict__ Wk,
    const float* __restrict__ Wv, const float* __restrict__ Wp,
    __hip_bfloat16* __restrict__ Wqkv, __hip_bfloat16* __restrict__ Wpb) {
  int m = blockIdx.y;
  const float* src = m == 0 ? Wq : m == 1 ? Wk : m == 2 ? Wv : Wp;
  __hip_bfloat16* dst = m < 3 ? Wqkv + (size_t)m * 262144 : Wpb;
  int i = blockIdx.x * 256 + threadIdx.x;
  float4 v = ((const float4*)src)[i];
  ushort4 o;
  o.x = bf16_bits(v.x); o.y = bf16_bits(v.y);
  o.z = bf16_bits(v.z); o.w = bf16_bits(v.w);
  ((ushort4*)dst)[i] = o;
}

// ---------------- normalize + transpose: x [B][C][L] -> hnT [B][L][C] bf16 ----
__global__ __launch_bounds__(256) void norm_t(
    const float* __restrict__ x, const float* __restrict__ scl,
    const float* __restrict__ sft, __hip_bfloat16* __restrict__ hnT) {
  __shared__ float tile[32][33];
  int l0 = blockIdx.x * 32, c0 = blockIdx.y * 32, b = blockIdx.z;
  int t = threadIdx.x;
#pragma unroll
  for (int i = 0; i < 4; ++i) {
    int idx = t + i * 256;
    int cc = idx >> 5, ll = idx & 31;
    tile[cc][ll] = x[((size_t)(b * CC + c0 + cc)) * LL + l0 + ll];
  }
  __syncthreads();
#pragma unroll
  for (int i = 0; i < 2; ++i) {
    int idx = t + i * 256;
    int ll = idx >> 4, cc = (idx & 15) * 2;
    float v0 = tile[cc][ll] * scl[c0 + cc] + sft[c0 + cc];
    float v1 = tile[cc + 1][ll] * scl[c0 + cc + 1] + sft[c0 + cc + 1];
    ushort2 o; o.x = bf16_bits(v0); o.y = bf16_bits(v1);
    *(ushort2*)(hnT + ((size_t)(b * LL + l0 + ll)) * CC + c0 + cc) = o;
  }
}

// ---------------- softmax: one row per wave, bf16 in place ----------------
__global__ __launch_bounds__(256) void softmax_bf16(__hip_bfloat16* __restrict__ S) {
  int wave = threadIdx.x >> 6, lane = threadIdx.x & 63;
  size_t row = (size_t)blockIdx.x * 4 + wave;
  uint4* p = (uint4*)(S + row * 1024);  // 8 bf16 per uint4
  uint4 r0 = p[lane * 2], r1 = p[lane * 2 + 1];
  float f[16];
  unsigned int w[8] = {r0.x, r0.y, r0.z, r0.w, r1.x, r1.y, r1.z, r1.w};
#pragma unroll
  for (int i = 0; i < 8; ++i) { f[2 * i] = bits_lo(w[i]); f[2 * i + 1] = bits_hi(w[i]); }
  float mx = f[0];
#pragma unroll
  for (int i = 1; i < 16; ++i) mx = fmaxf(mx, f[i]);
  for (int m = 32; m; m >>= 1) mx = fmaxf(mx, __shfl_xor(mx, m, 64));
  float s = 0.f;
#pragma unroll
  for (int i = 0; i < 16; ++i) { f[i] = __expf(f[i] - mx); s += f[i]; }
  for (int m = 32; m; m >>= 1) s += __shfl_xor(s, m, 64);
  float inv = 1.f / s;
  unsigned int ow[8];
#pragma unroll
  for (int i = 0; i < 8; ++i) {
    unsigned int lo = bf16_bits(f[2 * i] * inv);
    unsigned int hi = bf16_bits(f[2 * i + 1] * inv);
    ow[i] = lo | (hi << 16);
  }
  uint4 o0 = {ow[0], ow[1], ow[2], ow[3]}, o1 = {ow[4], ow[5], ow[6], ow[7]};
  p[lane * 2] = o0; p[lane * 2 + 1] = o1;
}

// ---------------- GEMM core: acc[4][4] += A[128xK] * B[128xK]^T ----------------
// LDS layout per 128x32 tile: row-major, 32 bf16 (64B) per row, but the four
// 8-elem k-chunks within a row are XOR-swizzled: physical col = q ^ ((row>>1)&3).
// Loader fetch assignment matches (global_load_lds writes lane-linear), so
// fragment reads hit each bank-quad exactly twice per 16-lane phase (free).
__device__ __forceinline__ void gemm_core(
    const __hip_bfloat16* __restrict__ A, int lda,
    const __hip_bfloat16* __restrict__ B, int ldb, int K,
    __hip_bfloat16* sA, __hip_bfloat16* sB, f32x4 (&acc)[4][4]) {
  const int tid = threadIdx.x;
  const int wave = tid >> 6, lane = tid & 63;
  const int wm = (wave >> 1) * 64, wn = (wave & 1) * 64;
  const int row0 = tid >> 2;                                  // 0..63
  const int ke0 = (((tid & 3) ^ ((tid >> 3) & 3)) * 8);       // swizzled fetch chunk
  const int fr = lane & 15;
  const int q = lane >> 4;                                    // 0..3
  const int colA = ((q ^ ((fr >> 1) & 3)) * 8);               // swizzled read col
  for (int k0 = 0; k0 < K; k0 += 32) {
    __syncthreads();
#pragma unroll
    for (int it = 0; it < 2; ++it) {
      const __hip_bfloat16* ga = A + (size_t)(it * 64 + row0) * lda + (k0 + ke0);
      const __hip_bfloat16* gb = B + (size_t)(it * 64 + row0) * ldb + (k0 + ke0);
      __builtin_amdgcn_global_load_lds(
          (__attribute__((address_space(1))) void*)(void*)ga,
          (__attribute__((address_space(3))) void*)(sA + (it * 256 + wave * 64) * 8),
          16, 0, 0);
      __builtin_amdgcn_global_load_lds(
          (__attribute__((address_space(1))) void*)(void*)gb,
          (__attribute__((address_space(3))) void*)(sB + (it * 256 + wave * 64) * 8),
          16, 0, 0);
    }
    __syncthreads();
    bf16x8 af[4], bfr[4];
#pragma unroll
    for (int i = 0; i < 4; ++i) {
      af[i]  = *(const bf16x8*)(sA + (wm + i * 16 + fr) * 32 + colA);
      bfr[i] = *(const bf16x8*)(sB + (wn + i * 16 + fr) * 32 + colA);
    }
#pragma unroll
    for (int i = 0; i < 4; ++i)
#pragma unroll
      for (int j = 0; j < 4; ++j)
        acc[i][j] = __builtin_amdgcn_mfma_f32_16x16x32_bf16(af[i], bfr[j], acc[i][j], 0, 0, 0);
  }
}

// ---------------- fused QKV: [1536x512] x hnT -> qT,kT (transposed), v ---------
__global__ __launch_bounds__(256, 3) void gemm_qkv(
    const __hip_bfloat16* __restrict__ Wb, const __hip_bfloat16* __restrict__ hnT,
    __hip_bfloat16* __restrict__ qT, __hip_bfloat16* __restrict__ kT,
    __hip_bfloat16* __restrict__ vN,
    const float* __restrict__ bq, const float* __restrict__ bk,
    const float* __restrict__ bv) {
  __shared__ __align__(16) __hip_bfloat16 sA[128 * 32];
  __shared__ __align__(16) __hip_bfloat16 sB[128 * 32];
  const int bat = blockIdx.z;
  const int m0 = blockIdx.y * 128, n0 = blockIdx.x * 128;
  f32x4 acc[4][4] = {};
  gemm_core(Wb + (size_t)m0 * 512, 512,
            hnT + (size_t)bat * LL * CC + (size_t)n0 * 512, 512, 512, sA, sB, acc);
  const int lane = threadIdx.x & 63, wave = threadIdx.x >> 6;
  const int wm = (wave >> 1) * 64, wn = (wave & 1) * 64;
  const int crow = (lane >> 4) * 4, ccol = lane & 15;
  const int id = m0 >> 9;
  const int mloc0 = m0 & 511;
  const float* bias = id == 0 ? bq : id == 1 ? bk : bv;
  if (id < 2) {
    __hip_bfloat16* D = (id == 0 ? qT : kT) + (size_t)bat * LL * CC;
#pragma unroll
    for (int i = 0; i < 4; ++i) {
      int mg = mloc0 + wm + i * 16 + crow;
      float bv4[4];
#pragma unroll
      for (int r = 0; r < 4; ++r) bv4[r] = bias[mg + r];
#pragma unroll
      for (int j = 0; j < 4; ++j) {
        int ng = n0 + wn + j * 16 + ccol;
        ushort4 o;
        o.x = bf16_bits(acc[i][j][0] + bv4[0]);
        o.y = bf16_bits(acc[i][j][1] + bv4[1]);
        o.z = bf16_bits(acc[i][j][2] + bv4[2]);
        o.w = bf16_bits(acc[i][j][3] + bv4[3]);
        *(ushort4*)(D + (size_t)ng * 512 + mg) = o;
      }
    }
  } else {
    __hip_bfloat16* D = vN + (size_t)bat * CC * LL;
#pragma unroll
    for (int i = 0; i < 4; ++i) {
      int mg = mloc0 + wm + i * 16 + crow;
      float bv4[4];
#pragma unroll
      for (int r = 0; r < 4; ++r) bv4[r] = bias[mg + r];
#pragma unroll
      for (int j = 0; j < 4; ++j) {
        int ng = n0 + wn + j * 16 + ccol;
#pragma unroll
        for (int r = 0; r < 4; ++r)
          D[(size_t)(mg + r) * 1024 + ng] = __float2bfloat16(acc[i][j][r] + bv4[r]);
      }
    }
  }
}

// ---------------- generic GEMM: MODE 0 bf16 natural, MODE 3 fp32 +bias+resid --
template <int MODE, bool BIAS>
__global__ __launch_bounds__(256, 3) void gemm_tn(
    const __hip_bfloat16* __restrict__ A, int lda, size_t strideA,
    const __hip_bfloat16* __restrict__ B, int ldb, size_t strideB,
    void* __restrict__ Dp, int ldd, size_t strideD,
    const float* __restrict__ bias, float scale,
    const float* __restrict__ resid, size_t strideR, int K) {
  __shared__ __align__(16) __hip_bfloat16 sA[128 * 32];
  __shared__ __align__(16) __hip_bfloat16 sB[128 * 32];
  const int bat = blockIdx.z;
  const int m0 = blockIdx.y * 128, n0 = blockIdx.x * 128;
  f32x4 acc[4][4] = {};
  gemm_core(A + (size_t)bat * strideA + (size_t)m0 * lda, lda,
            B + (size_t)bat * strideB + (size_t)n0 * ldb, ldb, K, sA, sB, acc);
  const int lane = threadIdx.x & 63, wave = threadIdx.x >> 6;
  const int wm = (wave >> 1) * 64, wn = (wave & 1) * 64;
  const int crow = (lane >> 4) * 4, ccol = lane & 15;
  if constexpr (MODE == 0) {
    __hip_bfloat16* D = (__hip_bfloat16*)Dp + (size_t)bat * strideD;
#pragma unroll
    for (int i = 0; i < 4; ++i) {
      int mg = m0 + wm + i * 16 + crow;
      float bv4[4];
#pragma unroll
      for (int r = 0; r < 4; ++r) bv4[r] = BIAS ? bias[mg + r] : 0.f;
#pragma unroll
      for (int j = 0; j < 4; ++j) {
        int ng = n0 + wn + j * 16 + ccol;
#pragma unroll
        for (int r = 0; r < 4; ++r)
          D[(size_t)(mg + r) * ldd + ng] =
              __float2bfloat16(acc[i][j][r] * scale + bv4[r]);
      }
    }
  } else {
    float* D = (float*)Dp + (size_t)bat * strideD;
#pragma unroll
    for (int i = 0; i < 4; ++i) {
      int mg = m0 + wm + i * 16 + crow;
      float bv4[4];
#pragma unroll
      for (int r = 0; r < 4; ++r) bv4[r] = BIAS ? bias[mg + r] : 0.f;
#pragma unroll
      for (int j = 0; j < 4; ++j) {
        int ng = n0 + wn + j * 16 + ccol;
        const float* rsrc = resid + (size_t)bat * strideR + (size_t)mg * ldd + ng;
        float* dst = D + (size_t)mg * ldd + ng;
#pragma unroll
        for (int r = 0; r < 4; ++r)
          dst[(size_t)r * ldd] = acc[i][j][r] * scale + bv4[r] + rsrc[(size_t)r * ldd];
      }
    }
  }
}

extern "C" void kernel_launch(void* const* d_in, const int* in_sizes, int n_in,
                              void* d_out, int out_size, void* d_ws, size_t ws_size,
                              hipStream_t stream) {
  const float* x     = (const float*)d_in[0];
  const float* gamma = (const float*)d_in[1];
  const float* beta  = (const float*)d_in[2];
  const float* Wq    = (const float*)d_in[3];
  const float* bq    = (const float*)d_in[4];
  const float* Wk    = (const float*)d_in[5];
  const float* bk    = (const float*)d_in[6];
  const float* Wv    = (const float*)d_in[7];
  const float* bv    = (const float*)d_in[8];
  const float* Wp    = (const float*)d_in[9];
  const float* bp    = (const float*)d_in[10];
  float* out = (float*)d_out;

  char* ws = (char*)d_ws;
  float* scl = (float*)ws;
  float* sft = scl + 512;
  __hip_bfloat16* Wqkvb = (__hip_bfloat16*)(ws + 4096);   // 1536x512
  __hip_bfloat16* Wpb = Wqkvb + 786432;                   // 512x512
  __hip_bfloat16* hnT = Wpb + 262144;                     // [B][L][C]
  __hip_bfloat16* qT  = hnT + 8388608;                    // [B][L][C]
  __hip_bfloat16* kT  = qT + 8388608;                     // [B][L][C]
  __hip_bfloat16* vN  = kT + 8388608;                     // [B][C][L]
  __hip_bfloat16* Sb  = vN + 8388608;                     // [B][L][L] bf16
  __hip_bfloat16* HT  = hnT;                              // reuse after QKV

  bn_stats<<<512, 256, 0, stream>>>(x, gamma, beta, scl, sft);
  cast4<<<dim3(256, 4), 256, 0, stream>>>(Wq, Wk, Wv, Wp, Wqkvb, Wpb);
  norm_t<<<dim3(32, 16, 16), 256, 0, stream>>>(x, scl, sft, hnT);

  const size_t sLC = (size_t)LL * CC;
  const size_t sCL = (size_t)CC * LL;
  const size_t sLLb = (size_t)LL * LL;

  // fused QKV
  gemm_qkv<<<dim3(8, 12, 16), 256, 0, stream>>>(Wqkvb, hnT, qT, kT, vN, bq, bk, bv);
  // S = qT kT^T * C^-0.5 -> bf16 [L][L]
  gemm_tn<0, false><<<dim3(8, 8, 16), 256, 0, stream>>>(
      qT, 512, sLC, kT, 512, sLC, Sb, 1024, sLLb, nullptr,
      0.04419417382415922f, nullptr, 0, 512);
  softmax_bf16<<<4096, 256, 0, stream>>>(Sb);
  // HT = attn v^T -> [L][C] bf16
  gemm_tn<0, false><<<dim3(4, 8, 16), 256, 0, stream>>>(
      Sb, 1024, sLLb, vN, 1024, sCL, HT, 512, sLC, nullptr, 1.f, nullptr, 0, 1024);
  // out = Wp HT^T + bp + x -> fp32 [C][L]
  gemm_tn<3, true><<<dim3(8, 4, 16), 256, 0, stream>>>(
      Wpb, 512, 0, HT, 512, sLC, out, 1024, sCL, bp, 1.f, x, sCL, 512);
}